// Round 4
// baseline (742.916 us; speedup 1.0000x reference)
//
#include <hip/hip_runtime.h>
#include <hip/hip_bf16.h>

#define HIDDEN 1024
#define FFN    2816
#define NEXP   8
#define NTOK   2048

typedef __attribute__((ext_vector_type(8))) short short8;   // 8 bf16 = 4 VGPRs
typedef __attribute__((ext_vector_type(4))) short short4v;  // 4 bf16 = 8 B
typedef __attribute__((ext_vector_type(4))) float f32x4;

static __device__ __forceinline__ short f2bf(float f) {
    __hip_bfloat16 h = __float2bfloat16(f);
    return *(short*)&h;
}

// async 16-B global->LDS DMA (lane i lands at ldsbase + i*16)
static __device__ __forceinline__ void gl_lds16(const short* g, short* l) {
    __builtin_amdgcn_global_load_lds(
        (const __attribute__((address_space(1))) void*)g,
        (__attribute__((address_space(3))) void*)l, 16, 0, 0);
}

// ---------------- Router: logits -> softmax -> top2 -> per-expert lists ---------
__global__ void __launch_bounds__(64)
router_kernel(const float* __restrict__ x, const float* __restrict__ Wgate,
              int* __restrict__ counts, int* __restrict__ tok,
              float* __restrict__ wts)
{
    int t = blockIdx.x;
    int lane = threadIdx.x;
    float acc[NEXP];
#pragma unroll
    for (int e = 0; e < NEXP; e++) acc[e] = 0.f;
    const float* xrow = x + (size_t)t * HIDDEN;
    for (int h = lane; h < HIDDEN; h += 64) {
        float xv = xrow[h];
#pragma unroll
        for (int e = 0; e < NEXP; e++) acc[e] += xv * Wgate[e * HIDDEN + h];
    }
#pragma unroll
    for (int off = 32; off > 0; off >>= 1) {
#pragma unroll
        for (int e = 0; e < NEXP; e++) acc[e] += __shfl_down(acc[e], off);
    }
    if (lane == 0) {
        float mx = acc[0];
#pragma unroll
        for (int e = 1; e < NEXP; e++) mx = fmaxf(mx, acc[e]);
        float p[NEXP];
#pragma unroll
        for (int e = 0; e < NEXP; e++) p[e] = __expf(acc[e] - mx);
        int i0 = 0; float p0 = p[0];
#pragma unroll
        for (int e = 1; e < NEXP; e++) if (p[e] > p0) { p0 = p[e]; i0 = e; }
        int i1 = -1; float p1 = -1.f;
#pragma unroll
        for (int e = 0; e < NEXP; e++) {
            if (e == i0) continue;
            if (p[e] > p1) { p1 = p[e]; i1 = e; }
        }
        float inv = 1.f / (p0 + p1);
        float w0 = p0 * inv, w1 = p1 * inv;
        int s0 = atomicAdd(&counts[i0], 1);
        tok[i0 * NTOK + s0] = t; wts[i0 * NTOK + s0] = w0;
        int s1 = atomicAdd(&counts[i1], 1);
        tok[i1 * NTOK + s1] = t; wts[i1 * NTOK + s1] = w1;
    }
}

// ---------------- fp32 -> bf16 pre-pass: one float4 per lane, fully coalesced ---
__global__ void __launch_bounds__(256)
cvt_all(const float* __restrict__ s0, const float* __restrict__ s1,
        const float* __restrict__ s2, const float* __restrict__ s3,
        short* __restrict__ d0, short* __restrict__ d1,
        short* __restrict__ d2, short* __restrict__ d3)
{
    const long long n0 = (long long)(NTOK * HIDDEN) / 4;        // float4 groups
    const long long nw = (long long)NEXP * FFN * HIDDEN / 4;
    long long tot = n0 + 3 * nw;
    for (long long i = (long long)blockIdx.x * 256 + threadIdx.x; i < tot;
         i += (long long)gridDim.x * 256) {
        const float* s; short* d; long long r;
        if (i < n0)               { s = s0; d = d0; r = i; }
        else if (i < n0 + nw)     { s = s1; d = d1; r = i - n0; }
        else if (i < n0 + 2 * nw) { s = s2; d = d2; r = i - n0 - nw; }
        else                      { s = s3; d = d3; r = i - n0 - 2 * nw; }
        float4 a = ((const float4*)s)[r];
        short4v o;
        o[0] = f2bf(a.x); o[1] = f2bf(a.y); o[2] = f2bf(a.z); o[3] = f2bf(a.w);
        *(short4v*)(d + 4 * r) = o;
    }
}

// ---------------- Stage A: 128x64 tile, dbuf async staging, 64x32/wave ---------
// LDS rows: 32 bf16 = 64 B, unpadded (DMA constraint). XOR chunk swizzle
// (c -> c ^ ((row>>1)&3)): conflict-free ds_read_b128 (verified 0 conflicts R3).
__global__ void __launch_bounds__(256, 3)
ffn1_v4(const short* __restrict__ xbf, const short* __restrict__ Wgbf,
        const short* __restrict__ Wubf, const int* __restrict__ counts,
        const int* __restrict__ tok, short* __restrict__ hbuf)
{
    int e = blockIdx.z;
    int cnt = counts[e];
    int row0 = blockIdx.x * 128;
    if (row0 >= cnt) return;
    int off_e = 0;
#pragma unroll
    for (int i = 0; i < NEXP; i++) if (i < e) off_e += counts[i];
    int f0 = blockIdx.y * 64;

    __shared__ short Xs[2][128 * 32];
    __shared__ short Gs[2][64 * 32];
    __shared__ short Us[2][64 * 32];
    __shared__ int   stok[128];

    int tid = threadIdx.x;
    if (tid < 128) stok[tid] = tok[e * NTOK + min(row0 + tid, cnt - 1)];
    __syncthreads();

    int lane = tid & 63, w = tid >> 6;
    int l15 = lane & 15, lq = lane >> 4;
    int wm = (w & 1) * 64, wn = (w >> 1) * 32;

    int prow   = lane >> 2;                           // row within 16-row group
    int gchunk = (lane & 3) ^ ((lane >> 3) & 3);      // swizzled source chunk

    // X staging: wave w fills rows [w*32, w*32+32): 2 DMA/wave
    const short* xsrc[2];
    short* xdst[2][2];
#pragma unroll
    for (int j = 0; j < 2; j++) {
        int rbase = w * 32 + j * 16;
        xsrc[j] = xbf + (size_t)stok[rbase + prow] * HIDDEN + gchunk * 8;
        xdst[0][j] = &Xs[0][rbase * 32];
        xdst[1][j] = &Xs[1][rbase * 32];
    }
    // G/U staging: wave w fills rows [w*16, w*16+16): 1 DMA each
    int rb2 = w * 16;
    const short* gsrc = Wgbf + (size_t)e * FFN * HIDDEN + (size_t)(f0 + rb2 + prow) * HIDDEN + gchunk * 8;
    const short* usrc = Wubf + (size_t)e * FFN * HIDDEN + (size_t)(f0 + rb2 + prow) * HIDDEN + gchunk * 8;
    short* gdst[2] = { &Gs[0][rb2 * 32], &Gs[1][rb2 * 32] };
    short* udst[2] = { &Us[0][rb2 * 32], &Us[1][rb2 * 32] };

    int aoff[4], boff[2];
#pragma unroll
    for (int mi = 0; mi < 4; mi++) {
        int r = wm + mi * 16 + l15;
        aoff[mi] = r * 32 + (lq ^ ((r >> 1) & 3)) * 8;
    }
#pragma unroll
    for (int ni = 0; ni < 2; ni++) {
        int r = wn + ni * 16 + l15;
        boff[ni] = r * 32 + (lq ^ ((r >> 1) & 3)) * 8;
    }

    f32x4 cg[4][2], cu[4][2];
#pragma unroll
    for (int i = 0; i < 4; i++)
#pragma unroll
        for (int j = 0; j < 2; j++) { cg[i][j] = (f32x4)0.f; cu[i][j] = (f32x4)0.f; }

    // prologue: fill buf 0 with k=0
    gl_lds16(xsrc[0], xdst[0][0]);
    gl_lds16(xsrc[1], xdst[0][1]);
    gl_lds16(gsrc, gdst[0]);
    gl_lds16(usrc, udst[0]);

    int b = 0;
    for (int k0 = 0; k0 < HIDDEN; k0 += 32, b ^= 1) {
        __syncthreads();                 // drains DMA for buf b; prev compute done
        if (k0 + 32 < HIDDEN) {          // prefetch k+1 into other buffer
            int kn = k0 + 32;
            gl_lds16(xsrc[0] + kn, xdst[b ^ 1][0]);
            gl_lds16(xsrc[1] + kn, xdst[b ^ 1][1]);
            gl_lds16(gsrc + kn, gdst[b ^ 1]);
            gl_lds16(usrc + kn, udst[b ^ 1]);
        }
        short8 af[4], bg[2], bu[2];
#pragma unroll
        for (int mi = 0; mi < 4; mi++) af[mi] = *(const short8*)&Xs[b][aoff[mi]];
#pragma unroll
        for (int ni = 0; ni < 2; ni++) {
            bg[ni] = *(const short8*)&Gs[b][boff[ni]];
            bu[ni] = *(const short8*)&Us[b][boff[ni]];
        }
#pragma unroll
        for (int mi = 0; mi < 4; mi++)
#pragma unroll
            for (int ni = 0; ni < 2; ni++) {
                cg[mi][ni] = __builtin_amdgcn_mfma_f32_16x16x32_bf16(af[mi], bg[ni], cg[mi][ni], 0, 0, 0);
                cu[mi][ni] = __builtin_amdgcn_mfma_f32_16x16x32_bf16(af[mi], bu[ni], cu[mi][ni], 0, 0, 0);
            }
    }

    // epilogue: silu(g)*u -> bf16 hbuf.  C/D: col=lane&15, row=lq*4+reg
#pragma unroll
    for (int mi = 0; mi < 4; mi++)
#pragma unroll
        for (int r = 0; r < 4; r++) {
            int row = wm + mi * 16 + lq * 4 + r;
            int grow = row0 + row;
            if (grow < cnt) {
                short* hrow = hbuf + (size_t)(off_e + grow) * FFN + f0 + wn;
#pragma unroll
                for (int ni = 0; ni < 2; ni++) {
                    float g = cg[mi][ni][r], u = cu[mi][ni][r];
                    float h = g / (1.f + __expf(-g)) * u;
                    hrow[ni * 16 + l15] = f2bf(h);
                }
            }
        }
}

// ---------------- Stage B: 128x64 tile, dbuf, K split in 2 ---------------------
__global__ void __launch_bounds__(256, 4)
ffn2_v4(const short* __restrict__ hbuf, const short* __restrict__ Wdbf,
        const int* __restrict__ counts, const int* __restrict__ tok,
        const float* __restrict__ wts, float* __restrict__ out)
{
    int e = blockIdx.z;
    int cnt = counts[e];
    int row0 = blockIdx.x * 128;
    if (row0 >= cnt) return;
    int off_e = 0;
#pragma unroll
    for (int i = 0; i < NEXP; i++) if (i < e) off_e += counts[i];
    int h0    = (blockIdx.y >> 1) * 64;
    int kbase = (blockIdx.y & 1) * (FFN / 2);

    __shared__ short Hs[2][128 * 32];
    __shared__ short Ds[2][64 * 32];
    __shared__ int   stok[128];
    __shared__ float swt[128];

    int tid = threadIdx.x;
    if (tid < 128) {
        int rc = min(row0 + tid, cnt - 1);
        stok[tid] = tok[e * NTOK + rc];
        swt[tid]  = wts[e * NTOK + rc];
    }
    __syncthreads();

    int lane = tid & 63, w = tid >> 6;
    int l15 = lane & 15, lq = lane >> 4;
    int wm = (w & 1) * 64, wn = (w >> 1) * 32;

    int prow   = lane >> 2;
    int gchunk = (lane & 3) ^ ((lane >> 3) & 3);

    const short* hsrc[2];
    short* hdst[2][2];
#pragma unroll
    for (int j = 0; j < 2; j++) {
        int rbase = w * 32 + j * 16;
        hsrc[j] = hbuf + (size_t)(off_e + min(row0 + rbase + prow, cnt - 1)) * FFN + kbase + gchunk * 8;
        hdst[0][j] = &Hs[0][rbase * 32];
        hdst[1][j] = &Hs[1][rbase * 32];
    }
    int rb2 = w * 16;
    const short* dsrc = Wdbf + (size_t)e * HIDDEN * FFN + (size_t)(h0 + rb2 + prow) * FFN + kbase + gchunk * 8;
    short* ddst[2] = { &Ds[0][rb2 * 32], &Ds[1][rb2 * 32] };

    int aoff[4], boff[2];
#pragma unroll
    for (int mi = 0; mi < 4; mi++) {
        int r = wm + mi * 16 + l15;
        aoff[mi] = r * 32 + (lq ^ ((r >> 1) & 3)) * 8;
    }
#pragma unroll
    for (int ni = 0; ni < 2; ni++) {
        int r = wn + ni * 16 + l15;
        boff[ni] = r * 32 + (lq ^ ((r >> 1) & 3)) * 8;
    }

    f32x4 c[4][2];
#pragma unroll
    for (int i = 0; i < 4; i++)
#pragma unroll
        for (int j = 0; j < 2; j++) c[i][j] = (f32x4)0.f;

    gl_lds16(hsrc[0], hdst[0][0]);
    gl_lds16(hsrc[1], hdst[0][1]);
    gl_lds16(dsrc, ddst[0]);

    int b = 0;
    for (int k0 = 0; k0 < FFN / 2; k0 += 32, b ^= 1) {
        __syncthreads();
        if (k0 + 32 < FFN / 2) {
            int kn = k0 + 32;
            gl_lds16(hsrc[0] + kn, hdst[b ^ 1][0]);
            gl_lds16(hsrc[1] + kn, hdst[b ^ 1][1]);
            gl_lds16(dsrc + kn, ddst[b ^ 1]);
        }
        short8 af[4], bd[2];
#pragma unroll
        for (int mi = 0; mi < 4; mi++) af[mi] = *(const short8*)&Hs[b][aoff[mi]];
#pragma unroll
        for (int ni = 0; ni < 2; ni++) bd[ni] = *(const short8*)&Ds[b][boff[ni]];
#pragma unroll
        for (int mi = 0; mi < 4; mi++)
#pragma unroll
            for (int ni = 0; ni < 2; ni++)
                c[mi][ni] = __builtin_amdgcn_mfma_f32_16x16x32_bf16(af[mi], bd[ni], c[mi][ni], 0, 0, 0);
    }

#pragma unroll
    for (int mi = 0; mi < 4; mi++)
#pragma unroll
        for (int r = 0; r < 4; r++) {
            int row = wm + mi * 16 + lq * 4 + r;
            int grow = row0 + row;
            if (grow < cnt) {
                int t = stok[row];
                float wgt = swt[row];
                float* orow = out + (size_t)t * HIDDEN + h0 + wn;
#pragma unroll
                for (int ni = 0; ni < 2; ni++)
                    atomicAdd(&orow[ni * 16 + l15], wgt * c[mi][ni][r]);
            }
        }
}

extern "C" void kernel_launch(void* const* d_in, const int* in_sizes, int n_in,
                              void* d_out, int out_size, void* d_ws, size_t ws_size,
                              hipStream_t stream) {
    const float* x     = (const float*)d_in[0];
    const float* Wgate = (const float*)d_in[1];
    const float* Wg    = (const float*)d_in[2];
    const float* Wu    = (const float*)d_in[3];
    const float* Wd    = (const float*)d_in[4];
    float* out = (float*)d_out;

    char* ws = (char*)d_ws;
    int*   counts = (int*)ws;
    int*   tok    = (int*)(ws + 256);
    float* wts    = (float*)(ws + 256 + NEXP * NTOK * 4);

    const size_t base = 256 + 2 * (size_t)NEXP * NTOK * 4;   // 131328
    short* xbf  = (short*)(ws + base);
    short* wgbf = xbf  + (size_t)NTOK * HIDDEN;
    short* wubf = wgbf + (size_t)NEXP * FFN * HIDDEN;
    short* wdbf = wubf + (size_t)NEXP * FFN * HIDDEN;
    short* hbuf = wdbf + (size_t)NEXP * HIDDEN * FFN;

    hipMemsetAsync(counts, 0, 256, stream);
    hipMemsetAsync(out, 0, (size_t)out_size * sizeof(float), stream);

    router_kernel<<<NTOK, 64, 0, stream>>>(x, Wgate, counts, tok, wts);
    cvt_all<<<8192, 256, 0, stream>>>(x, Wg, Wu, Wd, xbf, wgbf, wubf, wdbf);

    dim3 g1(NTOK / 128, FFN / 64, NEXP);             // 16 x 44 x 8, early-exit
    ffn1_v4<<<g1, 256, 0, stream>>>(xbf, wgbf, wubf, counts, tok, hbuf);

    dim3 g2(NTOK / 128, (HIDDEN / 64) * 2, NEXP);    // 16 x 32 x 8 (K split 2)
    ffn2_v4<<<g2, 256, 0, stream>>>(hbuf, wdbf, counts, tok, wts, out);
}